// Round 10
// baseline (147.335 us; speedup 1.0000x reference)
//
#include <hip/hip_runtime.h>

// PointConv: B=4, N=16384, K=32, F=64
// out[p,f] = sum_k ( lrelu(rel(p,k) @ W1 + b1) @ W2 + b2 )[f] * x[idx[p,k], f]
//
// Round 10: coalesced x-gather (4 rows/instr float4, 8 instr/point, ~128 L1
// transactions vs R5/R9's ~512 divergent ones) + S-transpose through per-wave
// LDS scratch:
//   MFMA acc (C-layout, f=2m+c interleave) --b64--> swave[32][68] --float4-->
//   X-natural layout; fma; shfl_xor(16,32) column-reduce; lanes 0..15 store
//   one coalesced float4.
// No barriers in the loop (per-wave scratch, same-wave LDS ordering).
// Kept from R5/R9 (verified non-spilling): __launch_bounds__(256,2), unroll-1
// point loop, no loop-carried arrays, f16 packed h (v_pk_fma_f16),
// v_mfma_f32_32x32x16_f16, b2 folded into acc init, conflict-free W2 fragment
// LDS, 1-deep jm/rel_pos prefetch, XCD-aware batch swizzle.
// HARD RULES: no loop-carried private arrays (R6/R7 -> scratch); no tightened
// launch bounds (R4/R8 -> scratch).

#define NPTS   16384
#define KNB    32
#define F      64
#define BATCH  4
#define LOG2N  14
#define WPTS   8

typedef _Float16 h2     __attribute__((ext_vector_type(2)));
typedef _Float16 h8     __attribute__((ext_vector_type(8)));
typedef float    f32x16 __attribute__((ext_vector_type(16)));

__global__ __launch_bounds__(256, 2) void pointconv_mfma(
    const float* __restrict__ x,
    const float* __restrict__ pos,
    const int*   __restrict__ idx,
    const float* __restrict__ W1,
    const float* __restrict__ b1,
    const float* __restrict__ W2,
    const float* __restrict__ b2,
    float*       __restrict__ out)
{
    // w1p[g/2] = {wx,wx', wy,wy', wz,wz', b1,b1'} for g-pair (f16)
    __shared__ __align__(16) _Float16 w1p[32][8];
    // w2f[hf][t][c][m][j] = f16(W2[16t+8hf+j][2m+c]) — fragment-ordered
    __shared__ __align__(16) _Float16 w2f[2][4][2][32][8];
    // per-wave S scratch: S[k][f] fp32, row stride 68 words (uniform banks)
    __shared__ __align__(16) float swave[4][KNB][68];

    const int tid = threadIdx.x;
    if (tid < 32) {
        const int g = 2 * tid;
        w1p[tid][0] = (_Float16)W1[0 * F + g]; w1p[tid][1] = (_Float16)W1[0 * F + g + 1];
        w1p[tid][2] = (_Float16)W1[1 * F + g]; w1p[tid][3] = (_Float16)W1[1 * F + g + 1];
        w1p[tid][4] = (_Float16)W1[2 * F + g]; w1p[tid][5] = (_Float16)W1[2 * F + g + 1];
        w1p[tid][6] = (_Float16)b1[g];         w1p[tid][7] = (_Float16)b1[g + 1];
    }
#pragma unroll
    for (int r = 0; r < 16; ++r) {             // 4096 elems, coalesced global read
        const int e = r * 256 + tid;           // e = g*64 + f
        const int g = e >> 6, f = e & 63;
        w2f[(g >> 3) & 1][g >> 4][f & 1][f >> 1][g & 7] = (_Float16)W2[e];
    }
    __syncthreads();

    const int lane = tid & 63;
    const int wv   = tid >> 6;
    const int m    = lane & 31;   // MFMA row (neighbor slot) / f-pair index
    const int hf   = lane >> 5;   // k-half of A/B fragments
    const int q    = lane >> 4;   // row-group for the coalesced gather (0..3)
    const int fq   = lane & 15;   // f-quad for the gather/epilogue

    // B fragments: one conflict-free b128 each, held for all points
    h8 bfrag[4][2];
#pragma unroll
    for (int t = 0; t < 4; ++t)
#pragma unroll
        for (int c = 0; c < 2; ++c)
            bfrag[t][c] = *(const h8*)&w2f[hf][t][c][m][0];

    const float2 b2v = *(const float2*)(b2 + 2 * m);

    // ---- XCD-aware swizzle: blockIdx%8 -> XCD; 2 XCDs per batch ----
    const int gb    = blockIdx.x;
    const int xcd   = gb & 7;
    const int qq    = gb >> 3;
    const int batch = xcd >> 1;
    const int pg    = qq + ((xcd & 1) << 8);
    const int base  = batch << LOG2N;                              // b*N
    const int p0_s  = base + pg * (4 * WPTS) + wv * WPTS;          // uniform
    const float* __restrict__ xb4 = x + (size_t)base * F + 4 * fq; // gather base

    // ---- prologue: jm + rel_pos for point 0 (lane owns neighbor m) ----
    int jm;
    float rx, ry, rz;
    {
        jm = idx[p0_s * KNB + m];
        const int nr = base + jm;
        rx = pos[p0_s * 3 + 0] - pos[nr * 3 + 0];
        ry = pos[p0_s * 3 + 1] - pos[nr * 3 + 1];
        rz = pos[p0_s * 3 + 2] - pos[nr * 3 + 2];
    }

    const h2 c01 = { (_Float16)0.1f, (_Float16)0.1f };

#pragma unroll 1
    for (int i = 0; i < WPTS; ++i) {
        const int p_s = p0_s + i;                       // wave-uniform

        // ---- 1: coalesced x-gather — chunk c loads rows 4c..4c+3; 16 lanes
        //         per row read its 256 B as float4 (xs live across MFMA,
        //         same 32-reg footprint as R5's xv) ----
        float4 xs[8];
#pragma unroll
        for (int c = 0; c < 8; ++c) {
            const int jr = __shfl(jm, 4 * c + q);       // idx[p, 4c+q]
            xs[c] = *(const float4*)(xb4 + (size_t)jr * F);
        }

        // ---- 2: prefetch next point's jm + rel_pos (hidden under MFMA) ----
        int jmn = 0;
        float rxn = 0.f, ryn = 0.f, rzn = 0.f;
        if (i + 1 < WPTS) {
            jmn = idx[(p_s + 1) * KNB + m];
            const int nr = base + jmn;
            rxn = pos[(p_s + 1) * 3 + 0] - pos[nr * 3 + 0];
            ryn = pos[(p_s + 1) * 3 + 1] - pos[nr * 3 + 1];
            rzn = pos[(p_s + 1) * 3 + 2] - pos[nr * 3 + 2];
        }

        // ---- 3: h in packed f16 A-layout + MFMA (acc preloaded with b2) ----
        f32x16 acc0, acc1;
#pragma unroll
        for (int r = 0; r < 16; ++r) { acc0[r] = b2v.x; acc1[r] = b2v.y; }

        const h2 rxp = { (_Float16)rx, (_Float16)rx };
        const h2 ryp = { (_Float16)ry, (_Float16)ry };
        const h2 rzp = { (_Float16)rz, (_Float16)rz };

#pragma unroll
        for (int t = 0; t < 4; ++t) {
            h8 af;
#pragma unroll
            for (int jj = 0; jj < 4; ++jj) {
                const int g2 = 8 * t + 4 * hf + jj;              // g-pair index
                const h8 w = *(const h8*)&w1p[g2][0];            // b128 broadcast
                const h2 wx = __builtin_shufflevector(w, w, 0, 1);
                const h2 wy = __builtin_shufflevector(w, w, 2, 3);
                const h2 wz = __builtin_shufflevector(w, w, 4, 5);
                const h2 bb = __builtin_shufflevector(w, w, 6, 7);
                h2 hv = bb + rxp * wx;                           // v_pk_fma_f16
                hv = hv + ryp * wy;
                hv = hv + rzp * wz;
                hv = __builtin_elementwise_max(hv, hv * c01);    // leaky_relu(0.1)
                af[2 * jj]     = hv[0];
                af[2 * jj + 1] = hv[1];
            }
            acc0 = __builtin_amdgcn_mfma_f32_32x32x16_f16(af, bfrag[t][0], acc0, 0, 0, 0);
            acc1 = __builtin_amdgcn_mfma_f32_32x32x16_f16(af, bfrag[t][1], acc1, 0, 0, 0);
        }

        // ---- 4: S -> per-wave LDS scratch (b64: f=2m,2m+1 adjacent) ----
#pragma unroll
        for (int reg = 0; reg < 16; ++reg) {
            const int r = (reg & 3) + ((reg >> 2) << 3) + (hf << 2);
            *(float2*)&swave[wv][r][2 * m] = make_float2(acc0[reg], acc1[reg]);
        }

        // ---- 5: read S in X-layout, weighted accumulate ----
        float4 part = make_float4(0.f, 0.f, 0.f, 0.f);
#pragma unroll
        for (int c = 0; c < 8; ++c) {
            const float4 s4 = *(const float4*)&swave[wv][4 * c + q][4 * fq];
            part.x = fmaf(s4.x, xs[c].x, part.x);
            part.y = fmaf(s4.y, xs[c].y, part.y);
            part.z = fmaf(s4.z, xs[c].z, part.z);
            part.w = fmaf(s4.w, xs[c].w, part.w);
        }

        // ---- 6: reduce across the 4 row-groups (lanes L, L+16, L+32, L+48) ----
        part.x += __shfl_xor(part.x, 16);
        part.y += __shfl_xor(part.y, 16);
        part.z += __shfl_xor(part.z, 16);
        part.w += __shfl_xor(part.w, 16);
        part.x += __shfl_xor(part.x, 32);
        part.y += __shfl_xor(part.y, 32);
        part.z += __shfl_xor(part.z, 32);
        part.w += __shfl_xor(part.w, 32);

        if (lane < 16)
            *(float4*)(out + (size_t)p_s * F + 4 * fq) = part;   // 256 B coalesced

        jm = jmn; rx = rxn; ry = ryn; rz = rzn;
    }
}

extern "C" void kernel_launch(void* const* d_in, const int* in_sizes, int n_in,
                              void* d_out, int out_size, void* d_ws, size_t ws_size,
                              hipStream_t stream) {
    const float* x   = (const float*)d_in[0];
    const float* pos = (const float*)d_in[1];
    const int*   idx = (const int*)  d_in[2];
    const float* W1  = (const float*)d_in[3];
    const float* b1  = (const float*)d_in[4];
    const float* W2  = (const float*)d_in[5];
    const float* b2  = (const float*)d_in[6];
    float* out = (float*)d_out;

    dim3 grid((BATCH * NPTS) / (4 * WPTS));   // 2048 blocks; %8 -> XCD swizzle
    dim3 block(256);
    pointconv_mfma<<<grid, block, 0, stream>>>(x, pos, idx, W1, b1, W2, b2, out);
}